// Round 9
// baseline (22.875 us; speedup 1.0000x reference)
//
#include <hip/hip_runtime.h>
#include <math.h>

#define R_ 1.3f
#define NCOARSE 32
#define SAMPLES 383
#define BATCH 512
#define STEPSZ 0.0203125f                  // 2*1.3/32/2/2
#define INV_FINE_VLEN 24.615384615384617f  // 64 / 2.6
#define NT 14                              // tiles per ray (s < 224 can be inside)
#define SWS 224                            // samples handled by heavy kernel

using f32x4 = __attribute__((ext_vector_type(4))) float;
using s16x8 = __attribute__((ext_vector_type(8))) short;
using u32x4 = __attribute__((ext_vector_type(4))) unsigned int;
using bf16x2 = __attribute__((ext_vector_type(2))) __bf16;

__device__ __forceinline__ unsigned int packbf2(float lo, float hi) {
    bf16x2 v;
    v.x = (__bf16)lo;
    v.y = (__bf16)hi;
    return __builtin_bit_cast(unsigned int, v);
}

// Per-dim: summed weight W[t] and coarse index C[t] for fine-parity t.
__device__ __forceinline__ void dimwc(float p, float* W, int* C) {
    float post0 = fminf(fmaxf(floorf(p - 0.5f), 0.f), 63.f);
    float post1 = fminf(fmaxf(floorf(p + 0.5f), 0.f), 63.f);
    float w0 = 1.f - fabsf(p - (post0 + 0.5f));
    float w1 = 1.f - fabsf(p - (post1 + 0.5f));
    int i0 = (int)post0, i1 = (int)post1;
    int f0 = i0 & 1, f1 = i1 & 1;
    W[0] = (f0 == 0 ? w0 : 0.f) + (f1 == 0 ? w1 : 0.f);
    W[1] = (f0 == 1 ? w0 : 0.f) + (f1 == 1 ? w1 : 0.f);
    int c0 = i0 >> 1, c1 = i1 >> 1;
    C[0] = (f0 == 0) ? c0 : c1;
    C[1] = (f0 == 1) ? c0 : c1;
}

// Flat tile-parallel heavy kernel: wave = one (ray, tile). 4 waves/block.
__global__ __launch_bounds__(256, 4) void dp_tiles(
    const float* __restrict__ rays_o, const float* __restrict__ rays_d,
    const float* __restrict__ grid, const float* __restrict__ atoms,
    float* __restrict__ alpha_ws, float* __restrict__ sig_ws)
{
    __shared__ float araw[7168];        // 28 KB raw atoms; reused as D staging
    __shared__ u32x4 Bf[16][64];        // 16 KB B fragments

    const int tid = threadIdx.x;
    const int wid = tid >> 6, l = tid & 63;
    const int sl = l & 15, j8 = (l >> 4) * 8, fp = l >> 4;

    // ---- stage atoms coalesced into LDS (7168 f32 = 7 x f32x4 per thread) ----
    {
        const f32x4* a4 = (const f32x4*)atoms;
        f32x4* d4 = (f32x4*)araw;
#pragma unroll
        for (int i = 0; i < 7; ++i) d4[tid + 256 * i] = a4[tid + 256 * i];
    }

    // ---- wave -> (ray, tile) ----
    const int wid_g = blockIdx.x * 4 + wid;
    const unsigned bu = (unsigned)wid_g / NT;
    const int b = (int)bu;
    const int t = wid_g - b * NT;

    // ---- ray setup (wave-uniform; overlaps atom staging) ----
    const float ox = rays_o[3 * b], oy = rays_o[3 * b + 1], oz = rays_o[3 * b + 2];
    const float dx = rays_d[3 * b], dy = rays_d[3 * b + 1], dz = rays_d[3 * b + 2];
    const float start = fmaxf(fmaxf(
        fminf((R_ - ox) / dx, (-R_ - ox) / dx),
        fminf((R_ - oy) / dy, (-R_ - oy) / dy)),
        fminf((R_ - oz) / dz, (-R_ - oz) / dz));
    const float t_exit = fminf(fminf(
        fmaxf((R_ - ox) / dx, (-R_ - ox) / dx),
        fmaxf((R_ - oy) / dy, (-R_ - oy) / dy)),
        fmaxf((R_ - oz) / dz, (-R_ - oz) / dz));
    const int ns = (int)floorf((t_exit - start) / STEPSZ) + 2;
    const int ntiles = min(NT, (ns >> 4) + 2);

    const float lend = sqrtf(dx * dx + dy * dy + dz * dz);
    const float dist = STEPSZ * lend;
    const float inv = 1.f / lend;
    const float nx = dx * inv, ny = dy * inv, nz = dz * inv;
    float sh[9];
    sh[0] = 0.28209479177387814f;
    sh[1] = -0.48860251190291987f * ny;
    sh[2] = 0.48860251190291987f * nz;
    sh[3] = -0.48860251190291987f * nx;
    sh[4] = 1.0925484305920792f * nx * ny;
    sh[5] = -1.0925484305920792f * ny * nz;
    sh[6] = 0.31539156525252005f * (2.f * nz * nz - nx * nx - ny * ny);
    sh[7] = -1.0925484305920792f * nx * nz;
    sh[8] = 0.5462742152960396f * (nx * nx - ny * ny);

    __syncthreads();   // araw ready

    // ---- build Bf from LDS atoms: 4 slots per thread ----
#pragma unroll
    for (int i = 0; i < 4; ++i) {
        const int slot = tid + 256 * i;              // 0..1023
        const int ll = slot & 63, ntt = (slot >> 6) & 1, kb = slot >> 7;
        const int a0 = (ll >> 4) * 8, d = ntt * 16 + (ll & 15);
        u32x4 o = {0u, 0u, 0u, 0u};
        if (d < 28) {
#pragma unroll
            for (int e2 = 0; e2 < 4; ++e2)
                o[e2] = packbf2(araw[(kb * 32 + a0 + 2 * e2) * 28 + d],
                                araw[(kb * 32 + a0 + 2 * e2 + 1) * 28 + d]);
        }
        Bf[slot >> 6][ll] = o;
    }

    __syncthreads();   // Bf ready; araw now free -> reuse as D staging

    float* Dbuf = araw + wid * 544;    // 544 floats per wave (stride-33 rows)

    if (t < ntiles) {
        const int s = t * 16 + sl;
        const float tt = start + s * STEPSZ;
        const float px = ox + tt * dx, py = oy + tt * dy, pz = oz + tt * dz;
        const bool m = (px > -R_ && px < R_ && py > -R_ && py < R_ && pz > -R_ && pz < R_);

        float W0[2], W1[2], W2[2];
        int C0[2], C1[2], C2[2];
        dimwc((px + R_) * INV_FINE_VLEN, W0, C0);
        dimwc((py + R_) * INV_FINE_VLEN, W1, C1);
        dimwc((pz + R_) * INV_FINE_VLEN, W2, C2);
        const float msk = m ? 1.f : 0.f;

        f32x4 acc0 = {0.f, 0.f, 0.f, 0.f};
        f32x4 acc1 = {0.f, 0.f, 0.f, 0.f};
#pragma unroll
        for (int half = 0; half < 2; ++half) {
            f32x4 qa[4], qb[4];
            float wf[4];
#pragma unroll
            for (int k2 = 0; k2 < 4; ++k2) {
                const int kb = half * 4 + k2;
                const int fx = (kb >> 2) & 1, fy = (kb >> 1) & 1, fz = kb & 1;
                wf[k2] = msk * W0[fx] * W1[fy] * W2[fz];
                const int cf = (C0[fx] * NCOARSE + C1[fy]) * NCOARSE + C2[fz];
                const f32x4* gp = (const f32x4*)(grid + cf * 32 + j8);
                qa[k2] = gp[0];
                qb[k2] = gp[1];
            }
#pragma unroll
            for (int k2 = 0; k2 < 4; ++k2) {
                const int kb = half * 4 + k2;
                const float w = wf[k2];
                u32x4 o;
                o.x = packbf2(w * qa[k2].x, w * qa[k2].y);
                o.y = packbf2(w * qa[k2].z, w * qa[k2].w);
                o.z = packbf2(w * qb[k2].x, w * qb[k2].y);
                o.w = packbf2(w * qb[k2].z, w * qb[k2].w);
                const s16x8 af = __builtin_bit_cast(s16x8, o);
                acc0 = __builtin_amdgcn_mfma_f32_16x16x32_bf16(
                    af, __builtin_bit_cast(s16x8, Bf[kb * 2 + 0][l]), acc0, 0, 0, 0);
                acc1 = __builtin_amdgcn_mfma_f32_16x16x32_bf16(
                    af, __builtin_bit_cast(s16x8, Bf[kb * 2 + 1][l]), acc1, 0, 0, 0);
            }
        }

        // D -> LDS (row = sample slot, stride 33), then per-sample epilogue
#pragma unroll
        for (int r = 0; r < 4; ++r) {
            Dbuf[(4 * fp + r) * 33 + sl]      = acc0[r];
            Dbuf[(4 * fp + r) * 33 + sl + 16] = acc1[r];
        }
        const int s2 = l >> 2, c = l & 3;
        const int so = b * SWS + t * 16 + s2;
        if (c == 3) {
            const float sigma = fmaxf(Dbuf[s2 * 33 + 27], 0.f);
            alpha_ws[so] = 1.f - __expf(-sigma * dist);
        } else {
            float r_ = 0.f;
#pragma unroll
            for (int k = 0; k < 9; ++k) r_ += sh[k] * Dbuf[s2 * 33 + c * 9 + k];
            sig_ws[so * 3 + c] = __builtin_amdgcn_rcpf(1.f + __expf(-r_));
        }
    } else {
        // zero this tile's slice (deterministic ws contents every call)
        if (l < 16) alpha_ws[b * SWS + t * 16 + l] = 0.f;
        if (l < 48) sig_ws[(b * SWS + t * 16) * 3 + l] = 0.f;
    }
}

// One wave per ray: ordered cumprod scan + reductions + all out_alpha writes.
__global__ __launch_bounds__(64) void dp_comp(
    const float* __restrict__ rays_o, const float* __restrict__ rays_d,
    const float* __restrict__ alpha_ws, const float* __restrict__ sig_ws,
    float* __restrict__ rgb_out, float* __restrict__ out_alpha,
    float* __restrict__ depth_out, float* __restrict__ out_loss)
{
    const int b = blockIdx.x;
    const int l = threadIdx.x;
    if (b == 0 && l == 0) out_loss[0] = 0.f;

    const float ox = rays_o[3 * b], oy = rays_o[3 * b + 1], oz = rays_o[3 * b + 2];
    const float dx = rays_d[3 * b], dy = rays_d[3 * b + 1], dz = rays_d[3 * b + 2];
    const float start = fmaxf(fmaxf(
        fminf((R_ - ox) / dx, (-R_ - ox) / dx),
        fminf((R_ - oy) / dy, (-R_ - oy) / dy)),
        fminf((R_ - oz) / dz, (-R_ - oz) / dz));

    float Tacc = 1.f;
    float r0 = 0.f, r1 = 0.f, r2 = 0.f, sd = 0.f, sa = 0.f;
    for (int j = 0; j < 4; ++j) {          // 4 segments cover s < 256 >= SWS
        const int s = j * 64 + l;
        const bool v = s < SWS;
        const float a = v ? alpha_ws[b * SWS + s] : 0.f;
        if (s < SAMPLES) out_alpha[b * SAMPLES + s] = a;   // s in [SWS,256): zero
        float incl = v ? (1.f - a + 1e-10f) : 1.f;
#pragma unroll
        for (int off = 1; off < 64; off <<= 1) {
            const float tm = __shfl_up(incl, off, 64);
            if (l >= off) incl *= tm;
        }
        float excl = __shfl_up(incl, 1, 64);
        if (l == 0) excl = 1.f;
        const float T = Tacc * excl;
        const float al = v ? a * T : 0.f;
        if (v) {
            r0 += al * sig_ws[(b * SWS + s) * 3 + 0];
            r1 += al * sig_ws[(b * SWS + s) * 3 + 1];
            r2 += al * sig_ws[(b * SWS + s) * 3 + 2];
            sd += al * (start + s * STEPSZ);
            sa += al;
        }
        Tacc *= __shfl(incl, 63, 64);
    }
    // remaining out_alpha zeros: s in [256, 383)
#pragma unroll
    for (int j = 0; j < 2; ++j) {
        const int s = 256 + j * 64 + l;
        if (s < SAMPLES) out_alpha[b * SAMPLES + s] = 0.f;
    }
#pragma unroll
    for (int m2 = 32; m2 > 0; m2 >>= 1) {
        r0 += __shfl_xor(r0, m2, 64);
        r1 += __shfl_xor(r1, m2, 64);
        r2 += __shfl_xor(r2, m2, 64);
        sd += __shfl_xor(sd, m2, 64);
        sa += __shfl_xor(sa, m2, 64);
    }
    if (l == 0) {
        const float base = 1.f - sa;
        rgb_out[b * 3 + 0] = r0 + base;
        rgb_out[b * 3 + 1] = r1 + base;
        rgb_out[b * 3 + 2] = r2 + base;
        depth_out[b] = sd;
    }
}

extern "C" void kernel_launch(void* const* d_in, const int* in_sizes, int n_in,
                              void* d_out, int out_size, void* d_ws, size_t ws_size,
                              hipStream_t stream) {
    const float* rays_o = (const float*)d_in[0];
    const float* rays_d = (const float*)d_in[1];
    const float* grid   = (const float*)d_in[2];
    const float* atoms  = (const float*)d_in[3];
    float* out   = (float*)d_out;
    float* rgb   = out;                                        // [512,3]
    float* alpha = out + BATCH * 3;                            // [512,383]
    float* depth = out + BATCH * 3 + BATCH * SAMPLES;          // [512]
    float* loss  = out + BATCH * 3 + BATCH * SAMPLES + BATCH;  // scalar

    float* alpha_ws = (float*)d_ws;                            // [512*224]
    float* sig_ws   = (float*)d_ws + BATCH * SWS;              // [512*224*3]

    dp_tiles<<<dim3(BATCH * NT / 4), dim3(256), 0, stream>>>(
        rays_o, rays_d, grid, atoms, alpha_ws, sig_ws);
    dp_comp<<<dim3(BATCH), dim3(64), 0, stream>>>(
        rays_o, rays_d, alpha_ws, sig_ws, rgb, alpha, depth, loss);
}

// Round 10
// 16.039 us; speedup vs baseline: 1.4262x; 1.4262x over previous
//
#include <hip/hip_runtime.h>
#include <math.h>

#define R_ 1.3f
#define NCOARSE 32
#define SAMPLES 383
#define BATCH 512
#define STEPSZ 0.0203125f                  // 2*1.3/32/2/2
#define INV_FINE_VLEN 24.615384615384617f  // 64 / 2.6

using f32x4 = __attribute__((ext_vector_type(4))) float;
using s16x8 = __attribute__((ext_vector_type(8))) short;
using u32x4 = __attribute__((ext_vector_type(4))) unsigned int;
using bf16x2 = __attribute__((ext_vector_type(2))) __bf16;

// f32 pair -> packed bf16 (RNE); compiler emits v_cvt_pk_bf16_f32.
__device__ __forceinline__ unsigned int packbf2(float lo, float hi) {
    bf16x2 v;
    v.x = (__bf16)lo;
    v.y = (__bf16)hi;
    return __builtin_bit_cast(unsigned int, v);
}

// Per-dim: summed weight W[t] and coarse index C[t] for fine-parity t.
__device__ __forceinline__ void dimwc(float p, float* W, int* C) {
    float post0 = fminf(fmaxf(floorf(p - 0.5f), 0.f), 63.f);
    float post1 = fminf(fmaxf(floorf(p + 0.5f), 0.f), 63.f);
    float w0 = 1.f - fabsf(p - (post0 + 0.5f));
    float w1 = 1.f - fabsf(p - (post1 + 0.5f));
    int i0 = (int)post0, i1 = (int)post1;
    int f0 = i0 & 1, f1 = i1 & 1;
    W[0] = (f0 == 0 ? w0 : 0.f) + (f1 == 0 ? w1 : 0.f);
    W[1] = (f0 == 1 ? w0 : 0.f) + (f1 == 1 ? w1 : 0.f);
    int c0 = i0 >> 1, c1 = i1 >> 1;
    C[0] = (f0 == 0) ? c0 : c1;
    C[1] = (f0 == 1) ? c0 : c1;
}

// One ray per block, 8 waves. Coalesced atom staging -> LDS -> B fragments;
// araw reused as per-wave D staging after the build barrier.
__global__ __launch_bounds__(512, 2) void dp_fused(
    const float* __restrict__ rays_o, const float* __restrict__ rays_d,
    const float* __restrict__ grid, const float* __restrict__ atoms,
    float* __restrict__ out_rgb, float* __restrict__ out_alpha,
    float* __restrict__ out_depth, float* __restrict__ out_loss)
{
    __shared__ float araw[7168];        // 28 KB raw atoms; reused as D staging
    __shared__ u32x4 Bf[16][64];        // 16 KB: B fragments
    __shared__ float alpha_l[384];
    __shared__ float sig_l[384][3];
    __shared__ float segtot[8];
    __shared__ float part[6][5];

    const int b = blockIdx.x;
    const int tid = threadIdx.x;
    const int wid = tid >> 6, l = tid & 63;
    const int sl = l & 15, j8 = (l >> 4) * 8;

    // ---- coalesced atom staging: 1792 x f32x4 contiguous ----
    {
        const f32x4* a4 = (const f32x4*)atoms;
        f32x4* d4 = (f32x4*)araw;
#pragma unroll
        for (int i = 0; i < 4; ++i) {
            const int idx = tid + 512 * i;
            if (idx < 1792) d4[idx] = a4[idx];
        }
    }

    if (b == 0 && tid == 0) out_loss[0] = 0.f;

    // ---- zero alpha/sig staging ----
    if (tid < 384) alpha_l[tid] = 0.f;
    {
        float* sf = &sig_l[0][0];
        for (int i = tid; i < 384 * 3; i += 512) sf[i] = 0.f;
    }

    // ---- ray setup (block-uniform; overlaps staging loads) ----
    const float ox = rays_o[3 * b], oy = rays_o[3 * b + 1], oz = rays_o[3 * b + 2];
    const float dx = rays_d[3 * b], dy = rays_d[3 * b + 1], dz = rays_d[3 * b + 2];
    const float start = fmaxf(fmaxf(
        fminf((R_ - ox) / dx, (-R_ - ox) / dx),
        fminf((R_ - oy) / dy, (-R_ - oy) / dy)),
        fminf((R_ - oz) / dz, (-R_ - oz) / dz));
    const float t_exit = fminf(fminf(
        fmaxf((R_ - ox) / dx, (-R_ - ox) / dx),
        fmaxf((R_ - oy) / dy, (-R_ - oy) / dy)),
        fmaxf((R_ - oz) / dz, (-R_ - oz) / dz));
    const int ns = (int)floorf((t_exit - start) / STEPSZ) + 2;
    const int ntiles = min(24, (ns >> 4) + 2);

    const float lend = sqrtf(dx * dx + dy * dy + dz * dz);
    const float dist = STEPSZ * lend;
    const float inv = 1.f / lend;
    const float nx = dx * inv, ny = dy * inv, nz = dz * inv;
    float sh[9];
    sh[0] = 0.28209479177387814f;
    sh[1] = -0.48860251190291987f * ny;
    sh[2] = 0.48860251190291987f * nz;
    sh[3] = -0.48860251190291987f * nx;
    sh[4] = 1.0925484305920792f * nx * ny;
    sh[5] = -1.0925484305920792f * ny * nz;
    sh[6] = 0.31539156525252005f * (2.f * nz * nz - nx * nx - ny * ny);
    sh[7] = -1.0925484305920792f * nx * nz;
    sh[8] = 0.5462742152960396f * (nx * nx - ny * ny);

    __syncthreads();   // araw + zeroed staging visible

    // ---- build Bf from LDS atoms: 2 slots per thread ----
#pragma unroll
    for (int i = 0; i < 2; ++i) {
        const int slot = tid + 512 * i;              // 0..1023
        const int ll = slot & 63, ntt = (slot >> 6) & 1, kb = slot >> 7;
        const int a0 = (ll >> 4) * 8, d = ntt * 16 + (ll & 15);
        u32x4 o = {0u, 0u, 0u, 0u};
        if (d < 28) {
#pragma unroll
            for (int e2 = 0; e2 < 4; ++e2)
                o[e2] = packbf2(araw[(kb * 32 + a0 + 2 * e2) * 28 + d],
                                araw[(kb * 32 + a0 + 2 * e2 + 1) * 28 + d]);
        }
        Bf[slot >> 6][ll] = o;
    }

    __syncthreads();   // Bf ready; araw free -> reuse as D staging

    float* Dbuf = araw + wid * 544;    // 544 floats per wave (stride-33 rows)

    // ---- sample phase: wave w handles tiles {w, w+8, w+16} < ntiles ----
    for (int t = wid; t < ntiles; t += 8) {
        const int s = t * 16 + sl;
        const float tt = start + s * STEPSZ;
        const float px = ox + tt * dx, py = oy + tt * dy, pz = oz + tt * dz;
        const bool m = (s < SAMPLES) &&
                       (px > -R_ && px < R_ && py > -R_ && py < R_ && pz > -R_ && pz < R_);
        if (__ballot(m) == 0ull) continue;   // staging pre-zeroed

        float W0[2], W1[2], W2[2];
        int C0[2], C1[2], C2[2];
        dimwc((px + R_) * INV_FINE_VLEN, W0, C0);
        dimwc((py + R_) * INV_FINE_VLEN, W1, C1);
        dimwc((pz + R_) * INV_FINE_VLEN, W2, C2);
        const float msk = m ? 1.f : 0.f;

        f32x4 acc0 = {0.f, 0.f, 0.f, 0.f};
        f32x4 acc1 = {0.f, 0.f, 0.f, 0.f};

        // two halves of 4 corners: direct gather -> scale -> pack -> MFMA
#pragma unroll
        for (int half = 0; half < 2; ++half) {
            f32x4 qa[4], qb[4];
            float wf[4];
#pragma unroll
            for (int k2 = 0; k2 < 4; ++k2) {
                const int kb = half * 4 + k2;
                const int fx = (kb >> 2) & 1, fy = (kb >> 1) & 1, fz = kb & 1;
                wf[k2] = msk * W0[fx] * W1[fy] * W2[fz];
                const int cf = (C0[fx] * NCOARSE + C1[fy]) * NCOARSE + C2[fz];
                const f32x4* gp = (const f32x4*)(grid + cf * 32 + j8);
                qa[k2] = gp[0];
                qb[k2] = gp[1];
            }
#pragma unroll
            for (int k2 = 0; k2 < 4; ++k2) {
                const int kb = half * 4 + k2;
                const float w = wf[k2];
                u32x4 o;
                o.x = packbf2(w * qa[k2].x, w * qa[k2].y);
                o.y = packbf2(w * qa[k2].z, w * qa[k2].w);
                o.z = packbf2(w * qb[k2].x, w * qb[k2].y);
                o.w = packbf2(w * qb[k2].z, w * qb[k2].w);
                const s16x8 af = __builtin_bit_cast(s16x8, o);
                acc0 = __builtin_amdgcn_mfma_f32_16x16x32_bf16(
                    af, __builtin_bit_cast(s16x8, Bf[kb * 2 + 0][l]), acc0, 0, 0, 0);
                acc1 = __builtin_amdgcn_mfma_f32_16x16x32_bf16(
                    af, __builtin_bit_cast(s16x8, Bf[kb * 2 + 1][l]), acc1, 0, 0, 0);
            }
        }

        // D -> LDS, row = sample slot, stride 33 (conflict-free reads)
        const int fp = l >> 4;
#pragma unroll
        for (int r = 0; r < 4; ++r) {
            Dbuf[(4 * fp + r) * 33 + sl]      = acc0[r];
            Dbuf[(4 * fp + r) * 33 + sl + 16] = acc1[r];
        }

        // epilogue: lane -> (sample s2, channel c)
        const int s2 = l >> 2, c = l & 3;
        const int so = t * 16 + s2;
        if (c == 3) {
            const float sigma = fmaxf(Dbuf[s2 * 33 + 27], 0.f);
            alpha_l[so] = 1.f - __expf(-sigma * dist);
        } else {
            float r_ = 0.f;
#pragma unroll
            for (int k = 0; k < 9; ++k) r_ += sh[k] * Dbuf[s2 * 33 + c * 9 + k];
            sig_l[so][c] = __builtin_amdgcn_rcpf(1.f + __expf(-r_));
        }
    }

    __syncthreads();

    // coalesced alpha store
    if (tid < SAMPLES) out_alpha[b * SAMPLES + tid] = alpha_l[tid];

    // ---- parallel compositing: 6 waves each scan a 64-sample segment ----
    float a_s = 0.f, incl = 1.f;
    if (wid < 6) {
        const int s = wid * 64 + l;
        const bool v = s < SAMPLES;
        a_s = v ? alpha_l[s] : 0.f;
        incl = v ? (1.f - a_s + 1e-10f) : 1.f;
#pragma unroll
        for (int off = 1; off < 64; off <<= 1) {
            const float tm = __shfl_up(incl, off, 64);
            if (l >= off) incl *= tm;
        }
        if (l == 63) segtot[wid] = incl;
    }
    __syncthreads();
    if (wid < 6) {
        float pre = 1.f;
        for (int k = 0; k < wid; ++k) pre *= segtot[k];   // wave-uniform
        float excl = __shfl_up(incl, 1, 64);
        if (l == 0) excl = 1.f;
        const int s = wid * 64 + l;
        const bool v = s < SAMPLES;
        const float al = v ? a_s * pre * excl : 0.f;
        float r0 = al * sig_l[s][0];
        float r1 = al * sig_l[s][1];
        float r2 = al * sig_l[s][2];
        float sd = al * (start + s * STEPSZ);
        float sa = al;
#pragma unroll
        for (int m2 = 32; m2 > 0; m2 >>= 1) {
            r0 += __shfl_xor(r0, m2, 64);
            r1 += __shfl_xor(r1, m2, 64);
            r2 += __shfl_xor(r2, m2, 64);
            sd += __shfl_xor(sd, m2, 64);
            sa += __shfl_xor(sa, m2, 64);
        }
        if (l == 0) {
            part[wid][0] = r0; part[wid][1] = r1; part[wid][2] = r2;
            part[wid][3] = sd; part[wid][4] = sa;
        }
    }
    __syncthreads();
    if (tid == 0) {
        float r0 = 0.f, r1 = 0.f, r2 = 0.f, sd = 0.f, sa = 0.f;
#pragma unroll
        for (int j = 0; j < 6; ++j) {
            r0 += part[j][0]; r1 += part[j][1]; r2 += part[j][2];
            sd += part[j][3]; sa += part[j][4];
        }
        const float base = 1.f - sa;
        out_rgb[b * 3 + 0] = r0 + base;
        out_rgb[b * 3 + 1] = r1 + base;
        out_rgb[b * 3 + 2] = r2 + base;
        out_depth[b] = sd;
    }
}

extern "C" void kernel_launch(void* const* d_in, const int* in_sizes, int n_in,
                              void* d_out, int out_size, void* d_ws, size_t ws_size,
                              hipStream_t stream) {
    const float* rays_o = (const float*)d_in[0];
    const float* rays_d = (const float*)d_in[1];
    const float* grid   = (const float*)d_in[2];
    const float* atoms  = (const float*)d_in[3];
    float* out   = (float*)d_out;
    float* rgb   = out;                                        // [512,3]
    float* alpha = out + BATCH * 3;                            // [512,383]
    float* depth = out + BATCH * 3 + BATCH * SAMPLES;          // [512]
    float* loss  = out + BATCH * 3 + BATCH * SAMPLES + BATCH;  // scalar

    dp_fused<<<dim3(BATCH), dim3(512), 0, stream>>>(
        rays_o, rays_d, grid, atoms, rgb, alpha, depth, loss);
}